// Round 8
// baseline (167.199 us; speedup 1.0000x reference)
//
#include <hip/hip_runtime.h>
#include <hip/hip_cooperative_groups.h>

namespace cg = cooperative_groups;

typedef __bf16 bf16_t;
typedef bf16_t bf16x4 __attribute__((ext_vector_type(4)));
typedef bf16_t bf16x8 __attribute__((ext_vector_type(8)));
typedef float f32x4 __attribute__((ext_vector_type(4)));
typedef float f32x16 __attribute__((ext_vector_type(16)));

namespace {
constexpr int kNH  = 16;
constexpr int kHD  = 64;
constexpr int kHID = kNH * kHD;   // 1024
constexpr int kSQ  = 2048;
constexpr int kKP  = 72;          // Q LDS pitch (bf16)
constexpr int kOmPitch = 68;      // epilogue float pitch
constexpr int kSmBytes = 71680;
constexpr int kKbElems = kNH * kSQ * kHD;  // 2,097,152 bf16 = 4 MB
}

// R18: FUSED prep+attention, one cooperative dispatch. Budget reconciliation
// across R0-R7: fill 44.5 + fattn 24.3 + "prep+gaps" ~24 = 93 on every round,
// and R7 proved the 24 is NOT prep's memory work (coalescing its worst access
// moved 0.4us; intrinsic prep ~5us). The residual is dispatch-boundary cost:
// launch gaps + serialization against the fill's writeback tail. Fix: delete
// the boundary. Grid is exactly co-resident (256 blocks x 512 thr = 1
// block/CU @ 71680B LDS), so grid.sync() is legal via cooperative launch.
// Phase 1 = identical pack work spread over this grid; device-scope fence +
// grid sync (cross-XCD Kb/Vb visibility, G16); phase 2 = R4 fattn verbatim.
__global__ __launch_bounds__(512, 2)
void fused_kernel(const float* __restrict__ Qg, const float* __restrict__ Kg,
                  const float* __restrict__ Vg, bf16_t* __restrict__ Kb,
                  bf16_t* __restrict__ Vb, float* __restrict__ Og) {
  __shared__ __align__(16) unsigned char smraw[kSmBytes];

  const int bid  = blockIdx.x;
  const int tid  = threadIdx.x;

  // ================= Phase 1: pack K (head-major bf16) + V (kappa order) ====
  {
    // K-pack: 262144 bf16x8 chunks over 131072 threads -> 2 each
    const int gtid = bid * 512 + tid;
    #pragma unroll
    for (int i = 0; i < 2; ++i) {
      const int o    = (gtid + i * 131072) * 8;   // bf16 out index in Kb
      const int head = o >> 17;                   // 131072 = 2048*64
      const int t    = (o >> 6) & 2047;
      const int d0   = o & 63;
      const float4 f0 = *(const float4*)(Kg + (size_t)t * kHID + head * kHD + d0);
      const float4 f1 = *(const float4*)(Kg + (size_t)t * kHID + head * kHD + d0 + 4);
      bf16x8 hk;
      hk[0] = (bf16_t)f0.x; hk[1] = (bf16_t)f0.y; hk[2] = (bf16_t)f0.z; hk[3] = (bf16_t)f0.w;
      hk[4] = (bf16_t)f1.x; hk[5] = (bf16_t)f1.y; hk[6] = (bf16_t)f1.z; hk[7] = (bf16_t)f1.w;
      *(bf16x8*)(Kb + o) = hk;
    }
    // V-pack: 1024 (head,tile) subtiles, 4 per block; 2 concurrent via 2 LDS
    // tiles (2 x 4KB), coalesced f32 stage -> bf16 LDS -> kappa gather.
    bf16_t (*ls)[32][64] = (bf16_t (*)[32][64])smraw;
    const int sub = tid >> 8;        // 0/1: which subtile this half-block does
    const int t8  = tid & 255;
    #pragma unroll
    for (int it = 0; it < 2; ++it) {
      const int vb   = bid * 4 + it * 2 + sub;    // 0..1023
      const int head = vb >> 6;
      const int tile = vb & 63;
      __syncthreads();                            // it=1: LDS reuse
      #pragma unroll
      for (int s = 0; s < 2; ++s) {
        const int idx = t8 + 256 * s;             // 512 float4s per subtile
        const int row = idx >> 4;
        const int c4  = (idx & 15) * 4;
        const float4 f =
            *(const float4*)(Vg + (size_t)(tile * 32 + row) * kHID + head * kHD + c4);
        bf16x4 hv4;
        hv4[0] = (bf16_t)f.x; hv4[1] = (bf16_t)f.y;
        hv4[2] = (bf16_t)f.z; hv4[3] = (bf16_t)f.w;
        *(bf16x4*)(&ls[sub][row][c4]) = hv4;
      }
      __syncthreads();
      const int lane = t8 >> 2;                   // 0..63
      const int hh   = lane >> 5;
      const int m31v = lane & 31;
      const int q    = t8 & 3;
      const int db   = q >> 1, tp = q & 1;
      bf16x8 hv;
      #pragma unroll
      for (int j = 0; j < 8; ++j)
        hv[j] = ls[sub][4 * hh + 16 * tp + (j & 3) + 8 * (j >> 2)][m31v + 32 * db];
      *(bf16x8*)(Vb + ((size_t)(head * 64 + tile) * 64 + lane) * 32 + (db * 16 + tp * 8)) = hv;
    }
  }
  __threadfence();              // device-scope release of Kb/Vb (cross-XCD)
  cg::this_grid().sync();       // all packs visible before any block proceeds

  // ================= Phase 2: attention (R4 structure, verbatim) ============
  bf16_t* qs = (bf16_t*)smraw;         // Q tile 64 x kKP (epilogue reuses LDS)

  const int head = bid & (kNH - 1);
  const int ip   = bid >> 4;          // 0..15: pair (31-ip, ip)

  const int wave = tid >> 6;          // 0..7: key-group, tiles jt == wave (mod 8)
  const int lane = tid & 63;
  const int h    = lane >> 5;
  const int m31  = lane & 31;

  const float kQScale = 0.125f * 1.44269504088896340736f;  // 1/sqrt(64)*log2(e)

  // per-lane fragment base pointers into the packed bf16 buffers
  const bf16_t* kfb = Kb + (size_t)head * (kSQ * kHD) + (size_t)m31 * kHD + 8 * h;
  const bf16_t* vfb = Vb + ((size_t)head * 64 * 64 + lane) * 32;

  for (int halfq = 0; halfq < 2; ++halfq) {
    const int mblk = halfq ? ip : (31 - ip);   // big q-tile first
    const int m0   = mblk * 64;
    const int mtk  = 2 * mblk + 1;             // last 32-key tile index

    // ---- stage Q tile (64 rows); barrier covers prior phase's LDS reads ----
    __syncthreads();
    #pragma unroll
    for (int i = 0; i < 2; ++i) {
      const int idx = tid + 512 * i;          // 1024 float4s
      const int row = idx >> 4;
      const int c4  = (idx & 15) * 4;
      const float4 f = *(const float4*)(Qg + (size_t)(m0 + row) * kHID + head * kHD + c4);
      bf16x4 qv;
      qv[0] = (bf16_t)(f.x * kQScale); qv[1] = (bf16_t)(f.y * kQScale);
      qv[2] = (bf16_t)(f.z * kQScale); qv[3] = (bf16_t)(f.w * kQScale);
      *(bf16x4*)(qs + row * kKP + c4) = qv;
    }
    __syncthreads();

    // ---- hoist Q fragments: loop-invariant, 8 x bf16x8 = 32 VGPRs ----
    bf16x8 qf00 = *(const bf16x8*)(qs + m31 * kKP +  0 + 8 * h);
    bf16x8 qf01 = *(const bf16x8*)(qs + m31 * kKP + 16 + 8 * h);
    bf16x8 qf02 = *(const bf16x8*)(qs + m31 * kKP + 32 + 8 * h);
    bf16x8 qf03 = *(const bf16x8*)(qs + m31 * kKP + 48 + 8 * h);
    bf16x8 qf10 = *(const bf16x8*)(qs + (32 + m31) * kKP +  0 + 8 * h);
    bf16x8 qf11 = *(const bf16x8*)(qs + (32 + m31) * kKP + 16 + 8 * h);
    bf16x8 qf12 = *(const bf16x8*)(qs + (32 + m31) * kKP + 32 + 8 * h);
    bf16x8 qf13 = *(const bf16x8*)(qs + (32 + m31) * kKP + 48 + 8 * h);

    // O^T accumulators; l partials per q-half
    f32x16 Oa00, Oa10, Oa01, Oa11;
    #pragma unroll
    for (int r = 0; r < 16; ++r) { Oa00[r] = 0.f; Oa10[r] = 0.f; Oa01[r] = 0.f; Oa11[r] = 0.f; }
    float lacc0 = 0.f, lacc1 = 0.f;

    // ---- single-buffered zero-LDS main loop ----
    bf16x8 k0, k1, k2, k3, v0, v1, v2, v3;
    int jt = wave;
    if (jt <= mtk) {
      const bf16_t* kp = kfb + (size_t)jt * 2048;
      k0 = *(const bf16x8*)(kp);      k1 = *(const bf16x8*)(kp + 16);
      k2 = *(const bf16x8*)(kp + 32); k3 = *(const bf16x8*)(kp + 48);
      const bf16_t* vp = vfb + (size_t)jt * 2048;
      v0 = *(const bf16x8*)(vp);      v1 = *(const bf16x8*)(vp + 8);
      v2 = *(const bf16x8*)(vp + 16); v3 = *(const bf16x8*)(vp + 24);
    }
    for (; jt <= mtk; jt += 8) {
      const int kv0  = jt * 32;
      const bool do0 = (kv0 <= m0);   // half0 live unless tile above diagonal

      // --- QK^T for both q-halves (K frags die here) ---
      f32x16 c0, c1;
      if (do0) {
        #pragma unroll
        for (int r = 0; r < 16; ++r) c0[r] = 0.f;
        c0 = __builtin_amdgcn_mfma_f32_32x32x16_bf16(k0, qf00, c0, 0, 0, 0);
        c0 = __builtin_amdgcn_mfma_f32_32x32x16_bf16(k1, qf01, c0, 0, 0, 0);
        c0 = __builtin_amdgcn_mfma_f32_32x32x16_bf16(k2, qf02, c0, 0, 0, 0);
        c0 = __builtin_amdgcn_mfma_f32_32x32x16_bf16(k3, qf03, c0, 0, 0, 0);
      }
      #pragma unroll
      for (int r = 0; r < 16; ++r) c1[r] = 0.f;
      c1 = __builtin_amdgcn_mfma_f32_32x32x16_bf16(k0, qf10, c1, 0, 0, 0);
      c1 = __builtin_amdgcn_mfma_f32_32x32x16_bf16(k1, qf11, c1, 0, 0, 0);
      c1 = __builtin_amdgcn_mfma_f32_32x32x16_bf16(k2, qf12, c1, 0, 0, 0);
      c1 = __builtin_amdgcn_mfma_f32_32x32x16_bf16(k3, qf13, c1, 0, 0, 0);

      // --- prefetch next K into the same regs (covers softmax+PV below) ---
      if (jt + 8 <= mtk) {
        const bf16_t* kp = kfb + (size_t)(jt + 8) * 2048;
        k0 = *(const bf16x8*)(kp);      k1 = *(const bf16x8*)(kp + 16);
        k2 = *(const bf16x8*)(kp + 32); k3 = *(const bf16x8*)(kp + 48);
      }

      // --- q-half 0: softmax + PV ---
      if (do0) {
        float p[16];
        if (kv0 == m0) {   // diagonal subtile
          #pragma unroll
          for (int r = 0; r < 16; ++r) {
            const int kr = (r & 3) + 8 * (r >> 2) + 4 * h;
            const float e = __builtin_amdgcn_exp2f(c0[r]);
            p[r] = (kr <= m31) ? e : 0.f;
            lacc0 += p[r];
          }
        } else {
          #pragma unroll
          for (int r = 0; r < 16; ++r) { p[r] = __builtin_amdgcn_exp2f(c0[r]); lacc0 += p[r]; }
        }
        bf16x8 pb0, pb1;
        #pragma unroll
        for (int j = 0; j < 8; ++j) { pb0[j] = (bf16_t)p[j]; pb1[j] = (bf16_t)p[8 + j]; }
        Oa00 = __builtin_amdgcn_mfma_f32_32x32x16_bf16(v0, pb0, Oa00, 0, 0, 0);
        Oa10 = __builtin_amdgcn_mfma_f32_32x32x16_bf16(v2, pb0, Oa10, 0, 0, 0);
        Oa00 = __builtin_amdgcn_mfma_f32_32x32x16_bf16(v1, pb1, Oa00, 0, 0, 0);
        Oa10 = __builtin_amdgcn_mfma_f32_32x32x16_bf16(v3, pb1, Oa10, 0, 0, 0);
      }

      // --- q-half 1: softmax + PV (V frags die here) ---
      {
        float p[16];
        if (kv0 == m0 + 32) {   // diagonal subtile
          #pragma unroll
          for (int r = 0; r < 16; ++r) {
            const int kr = (r & 3) + 8 * (r >> 2) + 4 * h;
            const float e = __builtin_amdgcn_exp2f(c1[r]);
            p[r] = (kr <= m31) ? e : 0.f;
            lacc1 += p[r];
          }
        } else {
          #pragma unroll
          for (int r = 0; r < 16; ++r) { p[r] = __builtin_amdgcn_exp2f(c1[r]); lacc1 += p[r]; }
        }
        bf16x8 pb0, pb1;
        #pragma unroll
        for (int j = 0; j < 8; ++j) { pb0[j] = (bf16_t)p[j]; pb1[j] = (bf16_t)p[8 + j]; }
        Oa01 = __builtin_amdgcn_mfma_f32_32x32x16_bf16(v0, pb0, Oa01, 0, 0, 0);
        Oa11 = __builtin_amdgcn_mfma_f32_32x32x16_bf16(v2, pb0, Oa11, 0, 0, 0);
        Oa01 = __builtin_amdgcn_mfma_f32_32x32x16_bf16(v1, pb1, Oa01, 0, 0, 0);
        Oa11 = __builtin_amdgcn_mfma_f32_32x32x16_bf16(v3, pb1, Oa11, 0, 0, 0);
      }

      // --- prefetch next V into the same regs (covers next tile's QK^T) ---
      if (jt + 8 <= mtk) {
        const bf16_t* vp = vfb + (size_t)(jt + 8) * 2048;
        v0 = *(const bf16x8*)(vp);      v1 = *(const bf16x8*)(vp + 8);
        v2 = *(const bf16x8*)(vp + 16); v3 = *(const bf16x8*)(vp + 24);
      }
    }

    // ---- epilogue: two passes (one per q-half), 8-way additive merge via LDS ----
    float* fv   = (float*)smraw;
    float* Om   = fv + wave * 32 * kOmPitch;   // per-wave 32 rows x 68
    float* larr = fv + 8 * 32 * kOmPitch;      // 8 waves x 64 l-partials

    #pragma unroll
    for (int qh = 0; qh < 2; ++qh) {
      __syncthreads();   // pass0: main-loop LDS dead; pass1: pass0 reads done
      {
        const f32x16& A0 = qh ? Oa01 : Oa00;   // d 0..31
        const f32x16& A1 = qh ? Oa11 : Oa10;   // d 32..63
        #pragma unroll
        for (int q = 0; q < 4; ++q) {
          f32x4 w0, w1;
          #pragma unroll
          for (int e = 0; e < 4; ++e) { w0[e] = A0[4 * q + e]; w1[e] = A1[4 * q + e]; }
          *(f32x4*)(Om + (size_t)m31 * kOmPitch + 8 * q + 4 * h)      = w0;
          *(f32x4*)(Om + (size_t)m31 * kOmPitch + 32 + 8 * q + 4 * h) = w1;
        }
        larr[wave * 64 + lane] = qh ? lacc1 : lacc0;
      }
      __syncthreads();
      {
        const int row = tid >> 4;             // 512 float4s: 32 rows x 16 cols
        const int c4  = (tid & 15) * 4;
        float l = 0.f;
        #pragma unroll
        for (int w = 0; w < 8; ++w)
          l += larr[w * 64 + row] + larr[w * 64 + 32 + row];
        const float inv = 1.f / l;
        f32x4 o;
        #pragma unroll
        for (int e = 0; e < 4; ++e) o[e] = 0.f;
        #pragma unroll
        for (int w = 0; w < 8; ++w) {
          const f32x4 a = *(const f32x4*)(fv + w * 32 * kOmPitch + (size_t)row * kOmPitch + c4);
          #pragma unroll
          for (int e = 0; e < 4; ++e) o[e] += a[e];
        }
        #pragma unroll
        for (int e = 0; e < 4; ++e) o[e] *= inv;
        *(f32x4*)(Og + (size_t)(m0 + 32 * qh + row) * kHID + head * kHD + c4) = o;
      }
    }
  }
}

extern "C" void kernel_launch(void* const* d_in, const int* in_sizes, int n_in,
                              void* d_out, int out_size, void* d_ws, size_t ws_size,
                              hipStream_t stream) {
  (void)in_sizes; (void)n_in; (void)ws_size; (void)out_size;
  const float* Q = (const float*)d_in[0];
  const float* K = (const float*)d_in[1];
  const float* V = (const float*)d_in[2];
  float* O = (float*)d_out;
  bf16_t* Kb = (bf16_t*)d_ws;            // 4 MB: [head][t][d] bf16
  bf16_t* Vb = Kb + kKbElems;            // 4 MB: pre-gathered kappa order
  void* args[] = {(void*)&Q, (void*)&K, (void*)&V, (void*)&Kb, (void*)&Vb, (void*)&O};
  // 256 blocks x 512 thr = 1 block/CU on 256 CUs: exactly co-resident.
  hipLaunchCooperativeKernel((const void*)fused_kernel, dim3(256), dim3(512),
                             args, 0, stream);
}

// Round 9
// 99.723 us; speedup vs baseline: 1.6766x; 1.6766x over previous
//
#include <hip/hip_runtime.h>

typedef __bf16 bf16_t;
typedef bf16_t bf16x4 __attribute__((ext_vector_type(4)));
typedef bf16_t bf16x8 __attribute__((ext_vector_type(8)));
typedef float f32x4 __attribute__((ext_vector_type(4)));
typedef float f32x16 __attribute__((ext_vector_type(16)));

namespace {
constexpr int kNH  = 16;
constexpr int kHD  = 64;
constexpr int kHID = kNH * kHD;   // 1024
constexpr int kSQ  = 2048;
constexpr int kKP  = 72;          // Q LDS pitch (bf16)
constexpr int kOmPitch = 68;      // epilogue float pitch
constexpr int kSmBytes = 71680;
}

// ---------------------------------------------------------------------------
// R19 prep: V-ONLY pack (12 MB traffic vs 32 MB). R8's budget model: prep runs
// in the poison-fill's writeback shadow (268 MB of dirty L2/L3 draining to
// HBM), so its duration scales with BYTES, not access pattern (R7's null).
// K-pack deleted; fattn reads K from f32 directly. 256 blocks x 4 subtiles,
// coalesced f32 stage -> bf16 LDS -> kappa gather (R7-proven transform).
// ---------------------------------------------------------------------------
__global__ __launch_bounds__(256)
void prep_v(const float* __restrict__ Vg, bf16_t* __restrict__ Vb) {
  __shared__ bf16_t ls[32][64];              // V subtile, bf16 (4 KB)
  const int tid = threadIdx.x;
  #pragma unroll 1
  for (int it = 0; it < 4; ++it) {
    const int vb   = blockIdx.x * 4 + it;    // 0..1023: one (head, tile)
    const int head = vb >> 6;
    const int tile = vb & 63;
    if (it) __syncthreads();                 // protect ls reuse across iters
    #pragma unroll
    for (int s = 0; s < 2; ++s) {
      const int idx = tid + 256 * s;         // 512 float4s
      const int row = idx >> 4;
      const int c4  = (idx & 15) * 4;
      const float4 f =
          *(const float4*)(Vg + (size_t)(tile * 32 + row) * kHID + head * kHD + c4);
      bf16x4 hv4;
      hv4[0] = (bf16_t)f.x; hv4[1] = (bf16_t)f.y;
      hv4[2] = (bf16_t)f.z; hv4[3] = (bf16_t)f.w;
      *(bf16x4*)(&ls[row][c4]) = hv4;
    }
    __syncthreads();
    const int lane = tid >> 2;               // 0..63
    const int hh   = lane >> 5;
    const int m31  = lane & 31;
    const int q    = tid & 3;
    const int db   = q >> 1, tp = q & 1;
    bf16x8 hv;
    #pragma unroll
    for (int j = 0; j < 8; ++j)
      hv[j] = ls[4 * hh + 16 * tp + (j & 3) + 8 * (j >> 2)][m31 + 32 * db];
    *(bf16x8*)(Vb + ((size_t)(head * 64 + tile) * 64 + lane) * 32 + (db * 16 + tp * 8)) = hv;
  }
}

// R19 fattn: R4's zero-LDS single-buffer structure, but K fragments load
// AT-USE from f32 Kg (8 x dwordx4 + 32 cvt per tile). (bf16_t)(f32) is the
// same rounding the pack did -> output bit-identical. At-use (not prefetched
// across backedge) keeps f32 staging transient: peak regs ~200 < R3's spill
// point. V still prefetched from Vb (kappa-packed, bf16).
__global__ __launch_bounds__(512, 2)
void fattn_kernel(const float* __restrict__ Qg, const float* __restrict__ Kg,
                  const bf16_t* __restrict__ Vb, float* __restrict__ Og) {
  __shared__ __align__(16) unsigned char smraw[kSmBytes];
  bf16_t* sm = (bf16_t*)smraw;
  bf16_t* qs = sm;                     // Q tile 64 x kKP (epilogue reuses LDS)

  const int bid  = blockIdx.x;
  const int head = bid & (kNH - 1);
  const int ip   = bid >> 4;          // 0..15: pair (31-ip, ip)

  const int tid  = threadIdx.x;
  const int wave = tid >> 6;          // 0..7: key-group, tiles jt == wave (mod 8)
  const int lane = tid & 63;
  const int h    = lane >> 5;
  const int m31  = lane & 31;

  const float kQScale = 0.125f * 1.44269504088896340736f;  // 1/sqrt(64)*log2(e)

  // per-lane fragment base pointers
  const float*  kgb = Kg + (size_t)m31 * kHID + head * kHD + 8 * h;  // f32 K
  const bf16_t* vfb = Vb + ((size_t)head * 64 * 64 + lane) * 32;

  for (int halfq = 0; halfq < 2; ++halfq) {
    const int mblk = halfq ? ip : (31 - ip);   // big q-tile first
    const int m0   = mblk * 64;
    const int mtk  = 2 * mblk + 1;             // last 32-key tile index

    // ---- stage Q tile (64 rows); barrier covers prior epilogue's LDS reads ----
    __syncthreads();
    #pragma unroll
    for (int i = 0; i < 2; ++i) {
      const int idx = tid + 512 * i;          // 1024 float4s
      const int row = idx >> 4;
      const int c4  = (idx & 15) * 4;
      const float4 f = *(const float4*)(Qg + (size_t)(m0 + row) * kHID + head * kHD + c4);
      bf16x4 qv;
      qv[0] = (bf16_t)(f.x * kQScale); qv[1] = (bf16_t)(f.y * kQScale);
      qv[2] = (bf16_t)(f.z * kQScale); qv[3] = (bf16_t)(f.w * kQScale);
      *(bf16x4*)(qs + row * kKP + c4) = qv;
    }
    __syncthreads();

    // ---- hoist Q fragments: loop-invariant, 8 x bf16x8 = 32 VGPRs ----
    bf16x8 qf00 = *(const bf16x8*)(qs + m31 * kKP +  0 + 8 * h);
    bf16x8 qf01 = *(const bf16x8*)(qs + m31 * kKP + 16 + 8 * h);
    bf16x8 qf02 = *(const bf16x8*)(qs + m31 * kKP + 32 + 8 * h);
    bf16x8 qf03 = *(const bf16x8*)(qs + m31 * kKP + 48 + 8 * h);
    bf16x8 qf10 = *(const bf16x8*)(qs + (32 + m31) * kKP +  0 + 8 * h);
    bf16x8 qf11 = *(const bf16x8*)(qs + (32 + m31) * kKP + 16 + 8 * h);
    bf16x8 qf12 = *(const bf16x8*)(qs + (32 + m31) * kKP + 32 + 8 * h);
    bf16x8 qf13 = *(const bf16x8*)(qs + (32 + m31) * kKP + 48 + 8 * h);

    // O^T accumulators; l partials per q-half
    f32x16 Oa00, Oa10, Oa01, Oa11;
    #pragma unroll
    for (int r = 0; r < 16; ++r) { Oa00[r] = 0.f; Oa10[r] = 0.f; Oa01[r] = 0.f; Oa11[r] = 0.f; }
    float lacc0 = 0.f, lacc1 = 0.f;

    // ---- V prefetch (single-buffered across backedge); K loaded at use ----
    bf16x8 v0, v1, v2, v3;
    int jt = wave;
    if (jt <= mtk) {
      const bf16_t* vp = vfb + (size_t)jt * 2048;
      v0 = *(const bf16x8*)(vp);      v1 = *(const bf16x8*)(vp + 8);
      v2 = *(const bf16x8*)(vp + 16); v3 = *(const bf16x8*)(vp + 24);
    }
    for (; jt <= mtk; jt += 8) {
      const int kv0  = jt * 32;
      const bool do0 = (kv0 <= m0);   // half0 live unless tile above diagonal

      // --- K fragments at-use: 8 x dwordx4 f32, one wait, cvt to bf16 ---
      const float* kp = kgb + (size_t)kv0 * kHID;
      const float4 ka0 = *(const float4*)(kp +  0);
      const float4 kb0 = *(const float4*)(kp +  4);
      const float4 ka1 = *(const float4*)(kp + 16);
      const float4 kb1 = *(const float4*)(kp + 20);
      const float4 ka2 = *(const float4*)(kp + 32);
      const float4 kb2 = *(const float4*)(kp + 36);
      const float4 ka3 = *(const float4*)(kp + 48);
      const float4 kb3 = *(const float4*)(kp + 52);
      bf16x8 k0, k1, k2, k3;
      k0[0]=(bf16_t)ka0.x; k0[1]=(bf16_t)ka0.y; k0[2]=(bf16_t)ka0.z; k0[3]=(bf16_t)ka0.w;
      k0[4]=(bf16_t)kb0.x; k0[5]=(bf16_t)kb0.y; k0[6]=(bf16_t)kb0.z; k0[7]=(bf16_t)kb0.w;
      k1[0]=(bf16_t)ka1.x; k1[1]=(bf16_t)ka1.y; k1[2]=(bf16_t)ka1.z; k1[3]=(bf16_t)ka1.w;
      k1[4]=(bf16_t)kb1.x; k1[5]=(bf16_t)kb1.y; k1[6]=(bf16_t)kb1.z; k1[7]=(bf16_t)kb1.w;
      k2[0]=(bf16_t)ka2.x; k2[1]=(bf16_t)ka2.y; k2[2]=(bf16_t)ka2.z; k2[3]=(bf16_t)ka2.w;
      k2[4]=(bf16_t)kb2.x; k2[5]=(bf16_t)kb2.y; k2[6]=(bf16_t)kb2.z; k2[7]=(bf16_t)kb2.w;
      k3[0]=(bf16_t)ka3.x; k3[1]=(bf16_t)ka3.y; k3[2]=(bf16_t)ka3.z; k3[3]=(bf16_t)ka3.w;
      k3[4]=(bf16_t)kb3.x; k3[5]=(bf16_t)kb3.y; k3[6]=(bf16_t)kb3.z; k3[7]=(bf16_t)kb3.w;

      // --- QK^T for both q-halves (K frags die here) ---
      f32x16 c0, c1;
      if (do0) {
        #pragma unroll
        for (int r = 0; r < 16; ++r) c0[r] = 0.f;
        c0 = __builtin_amdgcn_mfma_f32_32x32x16_bf16(k0, qf00, c0, 0, 0, 0);
        c0 = __builtin_amdgcn_mfma_f32_32x32x16_bf16(k1, qf01, c0, 0, 0, 0);
        c0 = __builtin_amdgcn_mfma_f32_32x32x16_bf16(k2, qf02, c0, 0, 0, 0);
        c0 = __builtin_amdgcn_mfma_f32_32x32x16_bf16(k3, qf03, c0, 0, 0, 0);
      }
      #pragma unroll
      for (int r = 0; r < 16; ++r) c1[r] = 0.f;
      c1 = __builtin_amdgcn_mfma_f32_32x32x16_bf16(k0, qf10, c1, 0, 0, 0);
      c1 = __builtin_amdgcn_mfma_f32_32x32x16_bf16(k1, qf11, c1, 0, 0, 0);
      c1 = __builtin_amdgcn_mfma_f32_32x32x16_bf16(k2, qf12, c1, 0, 0, 0);
      c1 = __builtin_amdgcn_mfma_f32_32x32x16_bf16(k3, qf13, c1, 0, 0, 0);

      // --- q-half 0: softmax + PV ---
      if (do0) {
        float p[16];
        if (kv0 == m0) {   // diagonal subtile
          #pragma unroll
          for (int r = 0; r < 16; ++r) {
            const int kr = (r & 3) + 8 * (r >> 2) + 4 * h;
            const float e = __builtin_amdgcn_exp2f(c0[r]);
            p[r] = (kr <= m31) ? e : 0.f;
            lacc0 += p[r];
          }
        } else {
          #pragma unroll
          for (int r = 0; r < 16; ++r) { p[r] = __builtin_amdgcn_exp2f(c0[r]); lacc0 += p[r]; }
        }
        bf16x8 pb0, pb1;
        #pragma unroll
        for (int j = 0; j < 8; ++j) { pb0[j] = (bf16_t)p[j]; pb1[j] = (bf16_t)p[8 + j]; }
        Oa00 = __builtin_amdgcn_mfma_f32_32x32x16_bf16(v0, pb0, Oa00, 0, 0, 0);
        Oa10 = __builtin_amdgcn_mfma_f32_32x32x16_bf16(v2, pb0, Oa10, 0, 0, 0);
        Oa00 = __builtin_amdgcn_mfma_f32_32x32x16_bf16(v1, pb1, Oa00, 0, 0, 0);
        Oa10 = __builtin_amdgcn_mfma_f32_32x32x16_bf16(v3, pb1, Oa10, 0, 0, 0);
      }

      // --- q-half 1: softmax + PV (V frags die here) ---
      {
        float p[16];
        if (kv0 == m0 + 32) {   // diagonal subtile
          #pragma unroll
          for (int r = 0; r < 16; ++r) {
            const int kr = (r & 3) + 8 * (r >> 2) + 4 * h;
            const float e = __builtin_amdgcn_exp2f(c1[r]);
            p[r] = (kr <= m31) ? e : 0.f;
            lacc1 += p[r];
          }
        } else {
          #pragma unroll
          for (int r = 0; r < 16; ++r) { p[r] = __builtin_amdgcn_exp2f(c1[r]); lacc1 += p[r]; }
        }
        bf16x8 pb0, pb1;
        #pragma unroll
        for (int j = 0; j < 8; ++j) { pb0[j] = (bf16_t)p[j]; pb1[j] = (bf16_t)p[8 + j]; }
        Oa01 = __builtin_amdgcn_mfma_f32_32x32x16_bf16(v0, pb0, Oa01, 0, 0, 0);
        Oa11 = __builtin_amdgcn_mfma_f32_32x32x16_bf16(v2, pb0, Oa11, 0, 0, 0);
        Oa01 = __builtin_amdgcn_mfma_f32_32x32x16_bf16(v1, pb1, Oa01, 0, 0, 0);
        Oa11 = __builtin_amdgcn_mfma_f32_32x32x16_bf16(v3, pb1, Oa11, 0, 0, 0);
      }

      // --- prefetch next V into the same regs (covers next tile's QK^T) ---
      if (jt + 8 <= mtk) {
        const bf16_t* vp = vfb + (size_t)(jt + 8) * 2048;
        v0 = *(const bf16x8*)(vp);      v1 = *(const bf16x8*)(vp + 8);
        v2 = *(const bf16x8*)(vp + 16); v3 = *(const bf16x8*)(vp + 24);
      }
    }

    // ---- epilogue: two passes (one per q-half), 8-way additive merge via LDS ----
    float* fv   = (float*)smraw;
    float* Om   = fv + wave * 32 * kOmPitch;   // per-wave 32 rows x 68
    float* larr = fv + 8 * 32 * kOmPitch;      // 8 waves x 64 l-partials

    #pragma unroll
    for (int qh = 0; qh < 2; ++qh) {
      __syncthreads();   // pass0: main-loop LDS dead; pass1: pass0 reads done
      {
        const f32x16& A0 = qh ? Oa01 : Oa00;   // d 0..31
        const f32x16& A1 = qh ? Oa11 : Oa10;   // d 32..63
        #pragma unroll
        for (int q = 0; q < 4; ++q) {
          f32x4 w0, w1;
          #pragma unroll
          for (int e = 0; e < 4; ++e) { w0[e] = A0[4 * q + e]; w1[e] = A1[4 * q + e]; }
          *(f32x4*)(Om + (size_t)m31 * kOmPitch + 8 * q + 4 * h)      = w0;
          *(f32x4*)(Om + (size_t)m31 * kOmPitch + 32 + 8 * q + 4 * h) = w1;
        }
        larr[wave * 64 + lane] = qh ? lacc1 : lacc0;
      }
      __syncthreads();
      {
        const int row = tid >> 4;             // 512 float4s: 32 rows x 16 cols
        const int c4  = (tid & 15) * 4;
        float l = 0.f;
        #pragma unroll
        for (int w = 0; w < 8; ++w)
          l += larr[w * 64 + row] + larr[w * 64 + 32 + row];
        const float inv = 1.f / l;
        f32x4 o;
        #pragma unroll
        for (int e = 0; e < 4; ++e) o[e] = 0.f;
        #pragma unroll
        for (int w = 0; w < 8; ++w) {
          const f32x4 a = *(const f32x4*)(fv + w * 32 * kOmPitch + (size_t)row * kOmPitch + c4);
          #pragma unroll
          for (int e = 0; e < 4; ++e) o[e] += a[e];
        }
        #pragma unroll
        for (int e = 0; e < 4; ++e) o[e] *= inv;
        *(f32x4*)(Og + (size_t)(m0 + 32 * qh + row) * kHID + head * kHD + c4) = o;
      }
    }
  }
}

extern "C" void kernel_launch(void* const* d_in, const int* in_sizes, int n_in,
                              void* d_out, int out_size, void* d_ws, size_t ws_size,
                              hipStream_t stream) {
  (void)in_sizes; (void)n_in; (void)ws_size; (void)out_size;
  const float* Q = (const float*)d_in[0];
  const float* K = (const float*)d_in[1];
  const float* V = (const float*)d_in[2];
  float* O = (float*)d_out;
  bf16_t* Vb = (bf16_t*)d_ws;            // 4 MB: pre-gathered kappa order
  hipLaunchKernelGGL(prep_v, dim3(256), dim3(256), 0, stream, V, Vb);
  dim3 grid(256);    // 16 heads x 16 q-tile PAIRS (31-ip, ip)
  dim3 block(512);   // 8 waves; zero-LDS main loop, K from f32 at-use
  hipLaunchKernelGGL(fattn_kernel, grid, block, 0, stream, Q, K, Vb, O);
}